// Round 9
// baseline (2216.902 us; speedup 1.0000x reference)
//
#include <hip/hip_runtime.h>
#include <math.h>

#define BATCH 64
#define TLEN 512
#define EMB 256
#define HID 256          // per-direction hidden
#define G4 1024          // 4*HID
#define KTAG 12
#define START_TAG 10
#define STOP_TAG 11
#define NEGV -10000.0f
#define SENT 0xFFFFFFFFu // -NaN sentinel: tanh-bounded h can never be this

#define LOG2E 1.4426950408889634f

typedef float f4 __attribute__((ext_vector_type(4)));

__device__ __forceinline__ float fsig(float x) {
    return __builtin_amdgcn_rcpf(1.f + __builtin_amdgcn_exp2f(-LOG2E * x));
}
__device__ __forceinline__ float ftanh(float x) {
    return 1.f - 2.f * __builtin_amdgcn_rcpf(1.f + __builtin_amdgcn_exp2f(2.f * LOG2E * x));
}
__device__ __forceinline__ void st_llc(float* p, float v) {
    __hip_atomic_store(p, v, __ATOMIC_RELAXED, __HIP_MEMORY_SCOPE_AGENT);
}
__device__ __forceinline__ unsigned ld_llc_u(const unsigned* p) {
    return __hip_atomic_load(p, __ATOMIC_RELAXED, __HIP_MEMORY_SCOPE_AGENT);
}
// 16-lane-group sum via DPP on the VALU pipe (no LDS-pipe ds_swizzle).
// Stages: quad_perm xor1 (0xB1), quad_perm xor2 (0x4E), ROW_HALF_MIRROR
// (0x141: i^7 within 8 == i^4 once quad-uniform), ROW_MIRROR (0x140:
// i^15 within 16 == i^8 once 8-uniform). Exact 16-lane tree sum.
// [v12 verified the 0xB1/0x4E/0x141 construction on HW, +270us]
__device__ __forceinline__ float red16(float a) {
    float t;
    t = __int_as_float(__builtin_amdgcn_update_dpp(
            0, __float_as_int(a), 0xB1, 0xF, 0xF, true));
    a += t;
    t = __int_as_float(__builtin_amdgcn_update_dpp(
            0, __float_as_int(a), 0x4E, 0xF, 0xF, true));
    a += t;
    t = __int_as_float(__builtin_amdgcn_update_dpp(
            0, __float_as_int(a), 0x141, 0xF, 0xF, true));
    a += t;
    t = __int_as_float(__builtin_amdgcn_update_dpp(
            0, __float_as_int(a), 0x140, 0xF, 0xF, true));
    a += t;
    return a;
}

// ---------------------------------------------------------------------------
// K1: fused embedding gather + input projection, both directions.
// x layout: x[r][gate*256+j], r = b*512+t. float4 epilogue stores.
// ---------------------------------------------------------------------------
#define MT 128
#define NT 128
#define KC 32
#define LDP 132

__global__ __launch_bounds__(256) void proj_kernel(
    const int* __restrict__ sentence, const float* __restrict__ emb,
    const float* __restrict__ Wf_ih, const float* __restrict__ Wb_ih,
    const float* __restrict__ bf_ih, const float* __restrict__ bf_hh,
    const float* __restrict__ bb_ih, const float* __restrict__ bb_hh,
    float* __restrict__ xf, float* __restrict__ xb) {
    int mtile = blockIdx.x;
    int ntile = blockIdx.y;
    int tid = threadIdx.x;

    __shared__ float As[KC][LDP];
    __shared__ float Bs[KC][LDP];
    __shared__ int tok[MT];

    int g2base = ntile * NT;
    const bool fwd = (g2base < 1024);
    const float* Wih = fwd ? Wf_ih : Wb_ih;
    const float* bia = fwd ? bf_ih : bb_ih;
    const float* bib = fwd ? bf_hh : bb_hh;
    float* dst       = fwd ? xf    : xb;
    int glb = g2base & 1023;

    if (tid < MT) tok[tid] = sentence[(size_t)mtile * MT + tid];
    __syncthreads();

    float acc[8][8];
#pragma unroll
    for (int i = 0; i < 8; ++i)
#pragma unroll
        for (int jj = 0; jj < 8; ++jj) acc[i][jj] = 0.f;

    int m0 = (tid & 15) * 8;
    int n0 = (tid >> 4) * 8;
    int lr = tid >> 3;
    int lk = (tid & 7) * 4;

    for (int k0 = 0; k0 < EMB; k0 += KC) {
#pragma unroll
        for (int i = 0; i < 4; ++i) {
            int r = lr + 32 * i;
            float4 v = *(const float4*)(emb + (size_t)tok[r] * EMB + k0 + lk);
            As[lk + 0][r] = v.x; As[lk + 1][r] = v.y;
            As[lk + 2][r] = v.z; As[lk + 3][r] = v.w;
            float4 w = *(const float4*)(Wih + (size_t)(glb + r) * EMB + k0 + lk);
            Bs[lk + 0][r] = w.x; Bs[lk + 1][r] = w.y;
            Bs[lk + 2][r] = w.z; Bs[lk + 3][r] = w.w;
        }
        __syncthreads();
#pragma unroll
        for (int kk = 0; kk < KC; ++kk) {
            float4 a0 = *(const float4*)&As[kk][m0];
            float4 a1 = *(const float4*)&As[kk][m0 + 4];
            float4 b0 = *(const float4*)&Bs[kk][n0];
            float4 b1 = *(const float4*)&Bs[kk][n0 + 4];
            float av[8] = {a0.x, a0.y, a0.z, a0.w, a1.x, a1.y, a1.z, a1.w};
            float bv[8] = {b0.x, b0.y, b0.z, b0.w, b1.x, b1.y, b1.z, b1.w};
#pragma unroll
            for (int i = 0; i < 8; ++i)
#pragma unroll
                for (int jj = 0; jj < 8; ++jj) acc[i][jj] += av[i] * bv[jj];
        }
        __syncthreads();
    }

    float bs[8];
#pragma unroll
    for (int jj = 0; jj < 8; ++jj) {
        int gl = glb + n0 + jj;
        bs[jj] = bia[gl] + bib[gl];
    }
#pragma unroll
    for (int i = 0; i < 8; ++i) {
        size_t r = (size_t)mtile * MT + m0 + i;
        float4 s0 = {acc[i][0] + bs[0], acc[i][1] + bs[1],
                     acc[i][2] + bs[2], acc[i][3] + bs[3]};
        float4 s1 = {acc[i][4] + bs[4], acc[i][5] + bs[5],
                     acc[i][6] + bs[6], acc[i][7] + bs[7]};
        *(float4*)(dst + r * (size_t)G4 + glb + n0)     = s0;
        *(float4*)(dst + r * (size_t)G4 + glb + n0 + 4) = s1;
    }
}

// ---------------------------------------------------------------------------
// K2: cooperative LSTM scan v14 = v12 compute restructured to 512 threads.
// Measured ladder: v5 1778 -> v8 2008 (W-BW exonerated) -> v10 1690 (1 bar +
// x-prefetch) -> v11 3320 (wave-autonomous poll REFUTED) -> v12 1418 (DPP
// reduce off LDS pipe, VALUBusy 48%). Register pinning of W is CLOSED:
// v6/v7/v13 (asm and volatile variants) all killed the container; the RA's
// in-loop ds_read of W (VGPR=132) is the design point.
// v12 residual: 1 wave/SIMD -> each wave's LDS-wait and poll-wait is fully
// exposed (VALU 1.33us + LDS 1.28us + poll ~0.6us barely overlap).
// v14: 512 threads / 8 waves / 2 per SIMD, k split 16 ways (kseg 0..15,
// 16 k each). Total FMA and LDS instrs per block UNCHANGED (256 FMA + 32
// b128 per thread); two waves per SIMD interleave -> LDS latency and poll
// stalls hide under the other wave's FMA stream.
//  * reduce: red16 (adds exact ROW_MIRROR stage to v12's verified chain)
//  * h chunk addressing: (kseg>>1)*36 + (kseg&1)*16 on the same padded
//    layout; 2-way bank aliasing only (free per m136)
//  * stage/poll: threads 0..255 (wave-uniform guard), identical protocol
//  * Wl[4][4][512] = 128 KiB, same total; no Wreg (always folded anyway)
// ---------------------------------------------------------------------------
__global__ __launch_bounds__(512, 2) void lstm_scan14(
    const float* __restrict__ xf, const float* __restrict__ xb,
    const float* __restrict__ Wf_hh, const float* __restrict__ Wb_hh,
    float* __restrict__ hcat) {
    int blk = blockIdx.x;
    int grp = blk & 31;          // members of a group share blk%8 (XCD heur.)
    int s   = blk >> 5;          // J-slice 0..7
    int d   = grp >> 4;          // direction
    int gq  = grp & 15;          // batch quartet
    int b0  = gq * 4;
    int tid = threadIdx.x;
    int kseg = tid & 15;         // 16 k-segments of 16 values
    int j    = tid >> 4;         // J index 0..31
    int J    = s * 32 + j;
    int bown = kseg & 3;

    __shared__ f4 Wl[4][4][512];      // 128 KiB: per-thread private W slices
    __shared__ float hsL[2][4 * 288]; // double-buffered h stage (9 KiB)

    // --- stage W: 4 gate-rows of J, k-slice [kseg*16, +16) into LDS ---
    const float* Whh = d ? Wb_hh : Wf_hh;
#pragma unroll
    for (int g = 0; g < 4; ++g)
#pragma unroll
        for (int q = 0; q < 4; ++q)
            Wl[g][q][tid] =
                *(const f4*)(Whh + (size_t)(g * 256 + J) * 256 + kseg * 16 + q * 4);

    const float* x = d ? xb : xf;
    const float* xrow0 = x + (size_t)(b0 + bown) * TLEN * G4 + J;
    int sw = (tid >> 5) * 36 + (tid & 31);       // valid for tid<256 stagers
    int hoff = (kseg >> 1) * 36 + (kseg & 1) * 16; // reader chunk offset
    float c = 0.f;

    // prologue: x for the first step
    const float* xr0 = xrow0 + (size_t)(d ? (TLEN - 1) : 0) * G4;
    float xc0 = xr0[0], xc1 = xr0[256], xc2 = xr0[512], xc3 = xr0[768];

    for (int i = 0; i < TLEN; ++i) {
        int t = d ? (TLEN - 1 - i) : i;
        int buf = i & 1;

        if (tid < 256) {                 // wave-uniform guard (waves 0..3)
            if (i == 0) {
#pragma unroll
                for (int bb = 0; bb < 4; ++bb) hsL[0][bb * 288 + sw] = 0.f;
            } else {
                int tp = d ? (t + 1) : (t - 1);
                const unsigned* base = (const unsigned*)hcat +
                    ((size_t)tp * BATCH + b0) * 512 + (size_t)d * HID + tid;
                unsigned u0, u1, u2, u3;
                for (;;) {
                    u0 = ld_llc_u(base);
                    u1 = ld_llc_u(base + 512);
                    u2 = ld_llc_u(base + 1024);
                    u3 = ld_llc_u(base + 1536);
                    if (u0 != SENT && u1 != SENT && u2 != SENT && u3 != SENT) break;
                    __builtin_amdgcn_s_sleep(1);
                }
                hsL[buf][0 * 288 + sw] = __uint_as_float(u0);
                hsL[buf][1 * 288 + sw] = __uint_as_float(u1);
                hsL[buf][2 * 288 + sw] = __uint_as_float(u2);
                hsL[buf][3 * 288 + sw] = __uint_as_float(u3);
            }
        }
        __syncthreads();   // single barrier per step (stage -> compute)

        // --- prefetch x for the NEXT step (consumed a full step later) ---
        int tn = (i == TLEN - 1) ? t : (d ? (t - 1) : (t + 1));
        const float* xrn = xrow0 + (size_t)tn * G4;
        float xn0 = xrn[0], xn1 = xrn[256], xn2 = xrn[512], xn3 = xrn[768];

        // --- q-outer: h f4 read once per (q,bb), W from (folded) LDS ---
        float a[4][4];               // [gate][bb], fully unrolled
#pragma unroll
        for (int g = 0; g < 4; ++g)
#pragma unroll
            for (int bb = 0; bb < 4; ++bb) a[g][bb] = 0.f;

        const float* hbase = hsL[buf] + hoff;
#pragma unroll
        for (int q = 0; q < 4; ++q) {
            f4 w0 = Wl[0][q][tid];
            f4 w1 = Wl[1][q][tid];
            f4 w2 = Wl[2][q][tid];
            f4 w3 = Wl[3][q][tid];
#pragma unroll
            for (int bb = 0; bb < 4; ++bb) {
                f4 h4 = *(const f4*)(hbase + bb * 288 + q * 4);
                a[0][bb] += w0.x*h4.x + w0.y*h4.y + w0.z*h4.z + w0.w*h4.w;
                a[1][bb] += w1.x*h4.x + w1.y*h4.y + w1.z*h4.z + w1.w*h4.w;
                a[2][bb] += w2.x*h4.x + w2.y*h4.y + w2.z*h4.z + w2.w*h4.w;
                a[3][bb] += w3.x*h4.x + w3.y*h4.y + w3.z*h4.z + w3.w*h4.w;
            }
        }

        // --- reduce over the 16-lane kseg group: DPP on the VALU pipe ---
#pragma unroll
        for (int bb = 0; bb < 4; ++bb) {
            a[0][bb] = red16(a[0][bb]);
            a[1][bb] = red16(a[1][bb]);
            a[2][bb] = red16(a[2][bb]);
            a[3][bb] = red16(a[3][bb]);
        }

        // --- select own batch (constant-index ternary chain, no scratch) ---
        float A0 = bown == 0 ? a[0][0] : bown == 1 ? a[0][1] : bown == 2 ? a[0][2] : a[0][3];
        float A1 = bown == 0 ? a[1][0] : bown == 1 ? a[1][1] : bown == 2 ? a[1][2] : a[1][3];
        float A2 = bown == 0 ? a[2][0] : bown == 1 ? a[2][1] : bown == 2 ? a[2][2] : a[2][3];
        float A3 = bown == 0 ? a[3][0] : bown == 1 ? a[3][1] : bown == 2 ? a[3][2] : a[3][3];

        float ig = fsig(A0 + xc0);
        float fg = fsig(A1 + xc1);
        float gg = ftanh(A2 + xc2);
        float og = fsig(A3 + xc3);
        c = fg * c + ig * gg;
        float h = og * ftanh(c);
        if (kseg < 4)
            st_llc(hcat + ((size_t)t * BATCH + b0 + bown) * 512
                        + (size_t)d * HID + J, h);

        xc0 = xn0; xc1 = xn1; xc2 = xn2; xc3 = xn3;
        // no trailing barrier: hsL double-buffered; next stage writes buf^1,
        // and stage of THIS buf recurs only after the next barrier generation.
    }
}

// ---------------------------------------------------------------------------
// K3: feats[t,b,k] = hcat[t,b,:] . W_out[k,:] + b_out[k].
// ---------------------------------------------------------------------------
__global__ __launch_bounds__(256) void feats_kernel(
    const float* __restrict__ hcat, const float* __restrict__ Wout,
    const float* __restrict__ bout, float* __restrict__ feats) {
    int wid = threadIdx.x >> 6;
    int lane = threadIdx.x & 63;
    size_t row = (size_t)blockIdx.x * 4 + wid;
    const float* hrow = hcat + row * 512;
    float4 h0 = *(const float4*)(hrow + lane * 8);
    float4 h1 = *(const float4*)(hrow + lane * 8 + 4);
    for (int k2 = 0; k2 < KTAG; ++k2) {
        const float* wr = Wout + (size_t)k2 * 512 + lane * 8;
        float4 w0 = *(const float4*)wr;
        float4 w1 = *(const float4*)(wr + 4);
        float p = h0.x * w0.x + h0.y * w0.y + h0.z * w0.z + h0.w * w0.w
                + h1.x * w1.x + h1.y * w1.y + h1.z * w1.z + h1.w * w1.w;
#pragma unroll
        for (int off = 32; off; off >>= 1) p += __shfl_down(p, off);
        if (lane == 0) feats[row * KTAG + k2] = p + bout[k2];
    }
}

// ---------------------------------------------------------------------------
// K4: Viterbi DP + backtrace. One wave per batch. 8-step feats prefetch ring.
// ---------------------------------------------------------------------------
__global__ __launch_bounds__(64) void viterbi_kernel(
    const float* __restrict__ feats, const float* __restrict__ trans,
    const int* __restrict__ slen, float* __restrict__ out) {
    int b = blockIdx.x;
    int lane = threadIdx.x;
    __shared__ unsigned char bp[TLEN][KTAG];

    int len = slen[b];
    float tr[KTAG];
#pragma unroll
    for (int p = 0; p < KTAG; ++p) tr[p] = 0.f;
    if (lane < KTAG) {
#pragma unroll
        for (int p = 0; p < KTAG; ++p) tr[p] = trans[lane * KTAG + p];
    }
    float tstop = (lane < KTAG) ? trans[STOP_TAG * KTAG + lane] : NEGV;
    float dp = (lane == START_TAG) ? 0.f : NEGV;

    float fb[8];
#pragma unroll
    for (int k = 0; k < 8; ++k)
        fb[k] = (lane < KTAG) ? feats[((size_t)k * BATCH + b) * KTAG + lane] : 0.f;

    for (int t0 = 0; t0 < TLEN; t0 += 8) {
#pragma unroll
        for (int u = 0; u < 8; ++u) {
            int t = t0 + u;
            float ftc = fb[u];
            int tn = t + 8;
            fb[u] = (tn < TLEN && lane < KTAG)
                        ? feats[((size_t)tn * BATCH + b) * KTAG + lane] : 0.f;
            float best = -1e30f;
            int arg = 0;
#pragma unroll
            for (int p = 0; p < KTAG; ++p) {
                float dpp = __shfl(dp, p);
                float sc = dpp + tr[p];
                if (sc > best) { best = sc; arg = p; }
            }
            bool m = (t < len);
            if (lane < KTAG) {
                dp = m ? (best + ftc) : dp;
                bp[t][lane] = (unsigned char)(m ? arg : lane);
            }
        }
    }

    float term = dp + tstop;
    float bbest = -1e30f;
    int barg = 0;
#pragma unroll
    for (int p = 0; p < KTAG; ++p) {
        float v = __shfl(term, p);
        if (v > bbest) { bbest = v; barg = p; }
    }
    if (lane == 0) {
        out[b] = bbest;
        float* path = out + BATCH + (size_t)b * TLEN;
        int tag = barg;
        for (int t = TLEN - 1; t >= 0; --t) {
            path[t] = (float)tag;
            tag = bp[t][tag];
        }
    }
}

// ---------------------------------------------------------------------------
extern "C" void kernel_launch(void* const* d_in, const int* in_sizes, int n_in,
                              void* d_out, int out_size, void* d_ws, size_t ws_size,
                              hipStream_t stream) {
    const int*   sentence = (const int*)d_in[0];
    const int*   slen     = (const int*)d_in[1];
    const float* emb      = (const float*)d_in[2];
    const float* Wf_ih    = (const float*)d_in[3];
    const float* Wf_hh    = (const float*)d_in[4];
    const float* bf_ih    = (const float*)d_in[5];
    const float* bf_hh    = (const float*)d_in[6];
    const float* Wb_ih    = (const float*)d_in[7];
    const float* Wb_hh    = (const float*)d_in[8];
    const float* bb_ih    = (const float*)d_in[9];
    const float* bb_hh    = (const float*)d_in[10];
    const float* W_out    = (const float*)d_in[11];
    const float* b_out    = (const float*)d_in[12];
    const float* trans    = (const float*)d_in[13];
    float* out = (float*)d_out;

    char* ws = (char*)d_ws;
    float* xf    = (float*)(ws);                       // 134,217,728 B
    float* xb    = (float*)(ws + 134217728ull);        // 134,217,728 B
    float* hcat  = (float*)(ws + 268435456ull);        //  67,108,864 B
    float* feats = (float*)(ws + 335544320ull);        //   1,572,864 B

    // sentinel-fill hcat: 0xFFFFFFFF = -NaN, unreachable for tanh-bounded h
    hipMemsetAsync(hcat, 0xFF, 67108864ull, stream);
    hipLaunchKernelGGL(proj_kernel, dim3(256, 16), dim3(256), 0, stream,
                       sentence, emb, Wf_ih, Wb_ih, bf_ih, bf_hh, bb_ih, bb_hh, xf, xb);
    hipLaunchKernelGGL(lstm_scan14, dim3(256), dim3(512), 0, stream,
                       xf, xb, Wf_hh, Wb_hh, hcat);
    hipLaunchKernelGGL(feats_kernel, dim3(8192), dim3(256), 0, stream,
                       hcat, W_out, b_out, feats);
    hipLaunchKernelGGL(viterbi_kernel, dim3(64), dim3(64), 0, stream,
                       feats, trans, slen, out);
}

// Round 10
// 2032.391 us; speedup vs baseline: 1.0908x; 1.0908x over previous
//
#include <hip/hip_runtime.h>
#include <math.h>

#define BATCH 64
#define TLEN 512
#define EMB 256
#define HID 256          // per-direction hidden
#define G4 1024          // 4*HID
#define KTAG 12
#define START_TAG 10
#define STOP_TAG 11
#define NEGV -10000.0f
#define SENT 0xFFFFFFFFu // -NaN sentinel: tanh-bounded h can never be this

#define LOG2E 1.4426950408889634f

typedef float f4 __attribute__((ext_vector_type(4)));

__device__ __forceinline__ float fsig(float x) {
    return __builtin_amdgcn_rcpf(1.f + __builtin_amdgcn_exp2f(-LOG2E * x));
}
__device__ __forceinline__ float ftanh(float x) {
    return 1.f - 2.f * __builtin_amdgcn_rcpf(1.f + __builtin_amdgcn_exp2f(2.f * LOG2E * x));
}
__device__ __forceinline__ void st_llc(float* p, float v) {
    __hip_atomic_store(p, v, __ATOMIC_RELAXED, __HIP_MEMORY_SCOPE_AGENT);
}
__device__ __forceinline__ unsigned ld_llc_u(const unsigned* p) {
    return __hip_atomic_load(p, __ATOMIC_RELAXED, __HIP_MEMORY_SCOPE_AGENT);
}
// 8-lane-group sum via DPP on the VALU pipe (replaces ds_swizzle shfl_xor,
// which serializes on the per-CU LDS pipe shared by all 4 waves).
// Steps: xor1 (quad_perm [1,0,3,2]=0xB1), xor2 (quad_perm [2,3,0,1]=0x4E),
// then row_half_mirror (0x141, lane i<->i^7 within 8). After xor1+xor2 the
// value is quad-uniform, so i^7 delivers the same value as i^4 ->
// BIT-IDENTICAL to the shfl_xor(1,2,4) reduction. [v12: verified, +270us]
__device__ __forceinline__ float red8(float a) {
    float t;
    t = __int_as_float(__builtin_amdgcn_update_dpp(
            0, __float_as_int(a), 0xB1, 0xF, 0xF, true));
    a += t;
    t = __int_as_float(__builtin_amdgcn_update_dpp(
            0, __float_as_int(a), 0x4E, 0xF, 0xF, true));
    a += t;
    t = __int_as_float(__builtin_amdgcn_update_dpp(
            0, __float_as_int(a), 0x141, 0xF, 0xF, true));
    a += t;
    return a;
}

// ---------------------------------------------------------------------------
// K1: fused embedding gather + input projection, both directions.
// x layout: x[r][gate*256+j], r = b*512+t. float4 epilogue stores.
// ---------------------------------------------------------------------------
#define MT 128
#define NT 128
#define KC 32
#define LDP 132

__global__ __launch_bounds__(256) void proj_kernel(
    const int* __restrict__ sentence, const float* __restrict__ emb,
    const float* __restrict__ Wf_ih, const float* __restrict__ Wb_ih,
    const float* __restrict__ bf_ih, const float* __restrict__ bf_hh,
    const float* __restrict__ bb_ih, const float* __restrict__ bb_hh,
    float* __restrict__ xf, float* __restrict__ xb) {
    int mtile = blockIdx.x;
    int ntile = blockIdx.y;
    int tid = threadIdx.x;

    __shared__ float As[KC][LDP];
    __shared__ float Bs[KC][LDP];
    __shared__ int tok[MT];

    int g2base = ntile * NT;
    const bool fwd = (g2base < 1024);
    const float* Wih = fwd ? Wf_ih : Wb_ih;
    const float* bia = fwd ? bf_ih : bb_ih;
    const float* bib = fwd ? bf_hh : bb_hh;
    float* dst       = fwd ? xf    : xb;
    int glb = g2base & 1023;

    if (tid < MT) tok[tid] = sentence[(size_t)mtile * MT + tid];
    __syncthreads();

    float acc[8][8];
#pragma unroll
    for (int i = 0; i < 8; ++i)
#pragma unroll
        for (int jj = 0; jj < 8; ++jj) acc[i][jj] = 0.f;

    int m0 = (tid & 15) * 8;
    int n0 = (tid >> 4) * 8;
    int lr = tid >> 3;
    int lk = (tid & 7) * 4;

    for (int k0 = 0; k0 < EMB; k0 += KC) {
#pragma unroll
        for (int i = 0; i < 4; ++i) {
            int r = lr + 32 * i;
            float4 v = *(const float4*)(emb + (size_t)tok[r] * EMB + k0 + lk);
            As[lk + 0][r] = v.x; As[lk + 1][r] = v.y;
            As[lk + 2][r] = v.z; As[lk + 3][r] = v.w;
            float4 w = *(const float4*)(Wih + (size_t)(glb + r) * EMB + k0 + lk);
            Bs[lk + 0][r] = w.x; Bs[lk + 1][r] = w.y;
            Bs[lk + 2][r] = w.z; Bs[lk + 3][r] = w.w;
        }
        __syncthreads();
#pragma unroll
        for (int kk = 0; kk < KC; ++kk) {
            float4 a0 = *(const float4*)&As[kk][m0];
            float4 a1 = *(const float4*)&As[kk][m0 + 4];
            float4 b0 = *(const float4*)&Bs[kk][n0];
            float4 b1 = *(const float4*)&Bs[kk][n0 + 4];
            float av[8] = {a0.x, a0.y, a0.z, a0.w, a1.x, a1.y, a1.z, a1.w};
            float bv[8] = {b0.x, b0.y, b0.z, b0.w, b1.x, b1.y, b1.z, b1.w};
#pragma unroll
            for (int i = 0; i < 8; ++i)
#pragma unroll
                for (int jj = 0; jj < 8; ++jj) acc[i][jj] += av[i] * bv[jj];
        }
        __syncthreads();
    }

    float bs[8];
#pragma unroll
    for (int jj = 0; jj < 8; ++jj) {
        int gl = glb + n0 + jj;
        bs[jj] = bia[gl] + bib[gl];
    }
#pragma unroll
    for (int i = 0; i < 8; ++i) {
        size_t r = (size_t)mtile * MT + m0 + i;
        float4 s0 = {acc[i][0] + bs[0], acc[i][1] + bs[1],
                     acc[i][2] + bs[2], acc[i][3] + bs[3]};
        float4 s1 = {acc[i][4] + bs[4], acc[i][5] + bs[5],
                     acc[i][6] + bs[6], acc[i][7] + bs[7]};
        *(float4*)(dst + r * (size_t)G4 + glb + n0)     = s0;
        *(float4*)(dst + r * (size_t)G4 + glb + n0 + 4) = s1;
    }
}

// ---------------------------------------------------------------------------
// K2: cooperative LSTM scan v15 = v12 with W streamed from L2 (no LDS-W).
// Measured ladder: v5 1778 (L2-W, 2 bar, shfl) -> v8 2008 (LDS-W: SLOWER,
// the one LDS pipe serializes what L2 streams in parallel) -> v10 1690
// (1 bar + x-prefetch) -> v12 1418 (DPP reduce off LDS pipe) -> v14 1635
// (512-thr TLP: bank conflicts + write-amp + x-dup taxes; reverted).
// v15 ports v10/v12's orthogonal wins back onto v5's W-access pattern:
//   * W read directly from global in the q-loop (L2-resident, 128 KB/step/CU
//     ~0.95us pipelined under VALU; per-XCD L2 demand ~2 TB/s < 4.3 ceiling).
//     This is the codegen the RA chose voluntarily in v4/v5 (VGPR 84) --
//     proven safe. Register pinning of W stays CLOSED (v6/v7/v13 all died).
//   * LDS pipe now carries ONLY h-reads + stage: 8448 b128/block/step
//     (~0.66us, was ~1.28us) -- conflict-free kseg*36 layout (v12-verified).
//   * single barrier + x-prefetch (v10) + red8 DPP reduce (v12) unchanged.
// Arithmetic order identical to v12 -> bit-identical results.
// ---------------------------------------------------------------------------
__global__ __launch_bounds__(256, 1) void lstm_scan15(
    const float* __restrict__ xf, const float* __restrict__ xb,
    const float* __restrict__ Wf_hh, const float* __restrict__ Wb_hh,
    float* __restrict__ hcat) {
    int blk = blockIdx.x;
    int grp = blk & 31;          // members of a group share blk%8 (XCD heur.)
    int s   = blk >> 5;          // J-slice 0..7
    int d   = grp >> 4;          // direction
    int gq  = grp & 15;          // batch quartet
    int b0  = gq * 4;
    int tid = threadIdx.x;
    int kseg = tid & 7;
    int j    = tid >> 3;
    int J    = s * 32 + j;
    int bown = kseg & 3;

    __shared__ float hsL[2][4 * 288]; // double-buffered h stage (9 KiB)

    // W base for this thread's 4 gate-rows, k-slice [kseg*32, +32)
    const float* Whh = d ? Wb_hh : Wf_hh;
    const float* Wbase = Whh + (size_t)J * 256 + kseg * 32;
    // gate g row offset: g * 256 rows * 256 cols = g * 65536 floats

    const float* x = d ? xb : xf;
    const float* xrow0 = x + (size_t)(b0 + bown) * TLEN * G4 + J;
    int sw = (tid >> 5) * 36 + (tid & 31);
    float c = 0.f;

    // prologue: x for the first step
    const float* xr0 = xrow0 + (size_t)(d ? (TLEN - 1) : 0) * G4;
    float xc0 = xr0[0], xc1 = xr0[256], xc2 = xr0[512], xc3 = xr0[768];

    for (int i = 0; i < TLEN; ++i) {
        int t = d ? (TLEN - 1 - i) : i;
        int buf = i & 1;

        if (i == 0) {
#pragma unroll
            for (int bb = 0; bb < 4; ++bb) hsL[0][bb * 288 + sw] = 0.f;
        } else {
            int tp = d ? (t + 1) : (t - 1);
            const unsigned* base = (const unsigned*)hcat +
                ((size_t)tp * BATCH + b0) * 512 + (size_t)d * HID + tid;
            unsigned u0, u1, u2, u3;
            for (;;) {
                u0 = ld_llc_u(base);
                u1 = ld_llc_u(base + 512);
                u2 = ld_llc_u(base + 1024);
                u3 = ld_llc_u(base + 1536);
                if (u0 != SENT && u1 != SENT && u2 != SENT && u3 != SENT) break;
                __builtin_amdgcn_s_sleep(1);
            }
            hsL[buf][0 * 288 + sw] = __uint_as_float(u0);
            hsL[buf][1 * 288 + sw] = __uint_as_float(u1);
            hsL[buf][2 * 288 + sw] = __uint_as_float(u2);
            hsL[buf][3 * 288 + sw] = __uint_as_float(u3);
        }
        __syncthreads();   // single barrier per step (stage -> compute)

        // --- prefetch x for the NEXT step (consumed a full step later) ---
        int tn = (i == TLEN - 1) ? t : (d ? (t - 1) : (t + 1));
        const float* xrn = xrow0 + (size_t)tn * G4;
        float xn0 = xrn[0], xn1 = xrn[256], xn2 = xrn[512], xn3 = xrn[768];

        // --- q-outer: W streamed from L2, h f4 read once per (q,bb) ---
        float a[4][4];               // [gate][bb], fully unrolled
#pragma unroll
        for (int g = 0; g < 4; ++g)
#pragma unroll
            for (int bb = 0; bb < 4; ++bb) a[g][bb] = 0.f;

        const float* hbase = hsL[buf] + kseg * 36;
#pragma unroll
        for (int q = 0; q < 8; ++q) {
            f4 w0 = *(const f4*)(Wbase + 0 * 65536 + q * 4);
            f4 w1 = *(const f4*)(Wbase + 1 * 65536 + q * 4);
            f4 w2 = *(const f4*)(Wbase + 2 * 65536 + q * 4);
            f4 w3 = *(const f4*)(Wbase + 3 * 65536 + q * 4);
#pragma unroll
            for (int bb = 0; bb < 4; ++bb) {
                f4 h4 = *(const f4*)(hbase + bb * 288 + q * 4);
                a[0][bb] += w0.x*h4.x + w0.y*h4.y + w0.z*h4.z + w0.w*h4.w;
                a[1][bb] += w1.x*h4.x + w1.y*h4.y + w1.z*h4.z + w1.w*h4.w;
                a[2][bb] += w2.x*h4.x + w2.y*h4.y + w2.z*h4.z + w2.w*h4.w;
                a[3][bb] += w3.x*h4.x + w3.y*h4.y + w3.z*h4.z + w3.w*h4.w;
            }
        }

        // --- reduce over the 8-lane kseg group: DPP on the VALU pipe ---
#pragma unroll
        for (int bb = 0; bb < 4; ++bb) {
            a[0][bb] = red8(a[0][bb]);
            a[1][bb] = red8(a[1][bb]);
            a[2][bb] = red8(a[2][bb]);
            a[3][bb] = red8(a[3][bb]);
        }

        // --- select own batch (constant-index ternary chain, no scratch) ---
        float A0 = bown == 0 ? a[0][0] : bown == 1 ? a[0][1] : bown == 2 ? a[0][2] : a[0][3];
        float A1 = bown == 0 ? a[1][0] : bown == 1 ? a[1][1] : bown == 2 ? a[1][2] : a[1][3];
        float A2 = bown == 0 ? a[2][0] : bown == 1 ? a[2][1] : bown == 2 ? a[2][2] : a[2][3];
        float A3 = bown == 0 ? a[3][0] : bown == 1 ? a[3][1] : bown == 2 ? a[3][2] : a[3][3];

        float ig = fsig(A0 + xc0);
        float fg = fsig(A1 + xc1);
        float gg = ftanh(A2 + xc2);
        float og = fsig(A3 + xc3);
        c = fg * c + ig * gg;
        float h = og * ftanh(c);
        if (kseg < 4)
            st_llc(hcat + ((size_t)t * BATCH + b0 + bown) * 512
                        + (size_t)d * HID + J, h);

        xc0 = xn0; xc1 = xn1; xc2 = xn2; xc3 = xn3;
        // no trailing barrier: hsL double-buffered; next stage writes buf^1,
        // and stage of THIS buf recurs only after the next barrier generation.
    }
}

// ---------------------------------------------------------------------------
// K3: feats[t,b,k] = hcat[t,b,:] . W_out[k,:] + b_out[k].
// ---------------------------------------------------------------------------
__global__ __launch_bounds__(256) void feats_kernel(
    const float* __restrict__ hcat, const float* __restrict__ Wout,
    const float* __restrict__ bout, float* __restrict__ feats) {
    int wid = threadIdx.x >> 6;
    int lane = threadIdx.x & 63;
    size_t row = (size_t)blockIdx.x * 4 + wid;
    const float* hrow = hcat + row * 512;
    float4 h0 = *(const float4*)(hrow + lane * 8);
    float4 h1 = *(const float4*)(hrow + lane * 8 + 4);
    for (int k2 = 0; k2 < KTAG; ++k2) {
        const float* wr = Wout + (size_t)k2 * 512 + lane * 8;
        float4 w0 = *(const float4*)wr;
        float4 w1 = *(const float4*)(wr + 4);
        float p = h0.x * w0.x + h0.y * w0.y + h0.z * w0.z + h0.w * w0.w
                + h1.x * w1.x + h1.y * w1.y + h1.z * w1.z + h1.w * w1.w;
#pragma unroll
        for (int off = 32; off; off >>= 1) p += __shfl_down(p, off);
        if (lane == 0) feats[row * KTAG + k2] = p + bout[k2];
    }
}

// ---------------------------------------------------------------------------
// K4: Viterbi DP + backtrace. One wave per batch. 8-step feats prefetch ring.
// ---------------------------------------------------------------------------
__global__ __launch_bounds__(64) void viterbi_kernel(
    const float* __restrict__ feats, const float* __restrict__ trans,
    const int* __restrict__ slen, float* __restrict__ out) {
    int b = blockIdx.x;
    int lane = threadIdx.x;
    __shared__ unsigned char bp[TLEN][KTAG];

    int len = slen[b];
    float tr[KTAG];
#pragma unroll
    for (int p = 0; p < KTAG; ++p) tr[p] = 0.f;
    if (lane < KTAG) {
#pragma unroll
        for (int p = 0; p < KTAG; ++p) tr[p] = trans[lane * KTAG + p];
    }
    float tstop = (lane < KTAG) ? trans[STOP_TAG * KTAG + lane] : NEGV;
    float dp = (lane == START_TAG) ? 0.f : NEGV;

    float fb[8];
#pragma unroll
    for (int k = 0; k < 8; ++k)
        fb[k] = (lane < KTAG) ? feats[((size_t)k * BATCH + b) * KTAG + lane] : 0.f;

    for (int t0 = 0; t0 < TLEN; t0 += 8) {
#pragma unroll
        for (int u = 0; u < 8; ++u) {
            int t = t0 + u;
            float ftc = fb[u];
            int tn = t + 8;
            fb[u] = (tn < TLEN && lane < KTAG)
                        ? feats[((size_t)tn * BATCH + b) * KTAG + lane] : 0.f;
            float best = -1e30f;
            int arg = 0;
#pragma unroll
            for (int p = 0; p < KTAG; ++p) {
                float dpp = __shfl(dp, p);
                float sc = dpp + tr[p];
                if (sc > best) { best = sc; arg = p; }
            }
            bool m = (t < len);
            if (lane < KTAG) {
                dp = m ? (best + ftc) : dp;
                bp[t][lane] = (unsigned char)(m ? arg : lane);
            }
        }
    }

    float term = dp + tstop;
    float bbest = -1e30f;
    int barg = 0;
#pragma unroll
    for (int p = 0; p < KTAG; ++p) {
        float v = __shfl(term, p);
        if (v > bbest) { bbest = v; barg = p; }
    }
    if (lane == 0) {
        out[b] = bbest;
        float* path = out + BATCH + (size_t)b * TLEN;
        int tag = barg;
        for (int t = TLEN - 1; t >= 0; --t) {
            path[t] = (float)tag;
            tag = bp[t][tag];
        }
    }
}

// ---------------------------------------------------------------------------
extern "C" void kernel_launch(void* const* d_in, const int* in_sizes, int n_in,
                              void* d_out, int out_size, void* d_ws, size_t ws_size,
                              hipStream_t stream) {
    const int*   sentence = (const int*)d_in[0];
    const int*   slen     = (const int*)d_in[1];
    const float* emb      = (const float*)d_in[2];
    const float* Wf_ih    = (const float*)d_in[3];
    const float* Wf_hh    = (const float*)d_in[4];
    const float* bf_ih    = (const float*)d_in[5];
    const float* bf_hh    = (const float*)d_in[6];
    const float* Wb_ih    = (const float*)d_in[7];
    const float* Wb_hh    = (const float*)d_in[8];
    const float* bb_ih    = (const float*)d_in[9];
    const float* bb_hh    = (const float*)d_in[10];
    const float* W_out    = (const float*)d_in[11];
    const float* b_out    = (const float*)d_in[12];
    const float* trans    = (const float*)d_in[13];
    float* out = (float*)d_out;

    char* ws = (char*)d_ws;
    float* xf    = (float*)(ws);                       // 134,217,728 B
    float* xb    = (float*)(ws + 134217728ull);        // 134,217,728 B
    float* hcat  = (float*)(ws + 268435456ull);        //  67,108,864 B
    float* feats = (float*)(ws + 335544320ull);        //   1,572,864 B

    // sentinel-fill hcat: 0xFFFFFFFF = -NaN, unreachable for tanh-bounded h
    hipMemsetAsync(hcat, 0xFF, 67108864ull, stream);
    hipLaunchKernelGGL(proj_kernel, dim3(256, 16), dim3(256), 0, stream,
                       sentence, emb, Wf_ih, Wb_ih, bf_ih, bf_hh, bb_ih, bb_hh, xf, xb);
    hipLaunchKernelGGL(lstm_scan15, dim3(256), dim3(256), 0, stream,
                       xf, xb, Wf_hh, Wb_hh, hcat);
    hipLaunchKernelGGL(feats_kernel, dim3(8192), dim3(256), 0, stream,
                       hcat, W_out, b_out, feats);
    hipLaunchKernelGGL(viterbi_kernel, dim3(64), dim3(64), 0, stream,
                       feats, trans, slen, out);
}